// Round 3
// baseline (166.015 us; speedup 1.0000x reference)
//
#include <hip/hip_runtime.h>

typedef short short8 __attribute__((ext_vector_type(8)));
typedef __bf16 bf16x8 __attribute__((ext_vector_type(8)));
typedef float floatx4 __attribute__((ext_vector_type(4)));

__device__ __forceinline__ float make_pow2(int e) {
  return __builtin_bit_cast(float, (unsigned)((e + 127) << 23));
}

typedef __attribute__((address_space(3))) void lds_void;
typedef const __attribute__((address_space(1))) void glob_void;
__device__ __forceinline__ void gload_lds16(const void* g, void* l) {
  __builtin_amdgcn_global_load_lds((glob_void*)g, (lds_void*)l, 16, 0, 0);
}

// ---------------- Phase 1: quantize weights -> bf16 in workspace ----------------
__global__ void quant_w_kernel(const float* __restrict__ w, unsigned short* __restrict__ qw) {
  int b = blockIdx.x;                 // 0..4607
  int row = b / 18, kb = b - row * 18;
  int t = threadIdx.x;                // 0..63
  int idx = row * 1152 + kb * 64 + t;
  float v = w[idx];
  float a = fabsf(v);
  #pragma unroll
  for (int off = 32; off; off >>= 1) a = fmaxf(a, __shfl_xor(a, off));
  float q = 0.f;
  if (a > 0.f) {
    int e = (int)((__builtin_bit_cast(unsigned, a) >> 23) & 0xffu) - 127;
    if (e < -126) e = -126;
    float inv = make_pow2(6 - e);
    float s   = make_pow2(e - 6);
    float r = rintf(v * inv);
    r = fminf(fmaxf(r, -128.f), 127.f);
    q = r * s;
  }
  qw[idx] = (unsigned short)(__builtin_bit_cast(unsigned, q) >> 16);
}

// ---------------- Phase 2: fused im2col + BFP-quantize + GEMM ----------------
// M=100352, N=256, K=1152. BM=64, BN=256, BK=64 (== BFP block). 256 thr = 4 waves,
// each wave owns a 64-col slab. Pipelined: gather(kb+1) in flight during MFMA(kb).
__global__ __launch_bounds__(256) void conv_bfp_kernel(
    const float* __restrict__ in, const unsigned short* __restrict__ qw,
    const float* __restrict__ bias, float* __restrict__ out) {
  __shared__ unsigned short As[64 * 64];    // 8 KB  [m][k] bf16, XOR-swizzled 16B chunks
  __shared__ unsigned short Bs[256 * 64];   // 32 KB [n][k] bf16, XOR-swizzled
  __shared__ float pmax[2][64][4];          // double-buffered cross-wave max

  const int mt = blockIdx.x;
  const int t = threadIdx.x;
  const int lane = t & 63;
  const int wave = __builtin_amdgcn_readfirstlane(t >> 6);

  // ---- pixel geometry (row m = lane; coalesced along x) ----
  const unsigned m = mt * 64u + lane;
  const unsigned nimg = m / 3136u;
  const unsigned py = m - nimg * 3136u;
  const int y = (int)(py / 56u);
  const int x = (int)(py - (unsigned)y * 56u);
  const int vbase = (int)((nimg * 401408u + (unsigned)y * 56u + (unsigned)x) * 4u);
  int vm = 0;
  #pragma unroll
  for (int i = 0; i < 3; ++i)
    #pragma unroll
    for (int j = 0; j < 3; ++j)
      if ((unsigned)(y + i - 1) < 56u && (unsigned)(x + j - 1) < 56u)
        vm |= 1 << (i * 3 + j);

  // ---- B staging geometry (wave w stages rows w*64..+63 via global_load_lds) ----
  const int l3 = lane >> 3, l7 = lane & 7;
  const char* bsrc = (const char*)qw + (size_t)((wave * 64 + l3) * 2304) + ((l7 ^ l3) * 16);
  char* bdst = (char*)Bs + wave * 8192;

  const int lr = lane & 15;
  const int lk = (lane >> 4) << 4;
  const int swz = (lr & 7) << 4;

  floatx4 acc[4][4] = {};

  auto gather = [&](float (&av)[16], int kb) {
    const int k0 = __builtin_amdgcn_readfirstlane(kb * 64 + wave * 16);
    #pragma unroll
    for (int u = 0; u < 16; ++u) {
      int k = k0 + u;                          // scalar
      int c = (int)((unsigned)k / 9u);
      int ij = k - c * 9;
      int soff = c * 3136 + (ij / 3) * 56 + (ij % 3) - 57;
      const char* pk = (const char*)in + (ptrdiff_t)soff * 4;
      float v = 0.f;
      if ((vm >> ij) & 1)
        v = *(const float*)(pk + vbase);
      av[u] = v;
    }
  };

  auto step = [&](float (&avc)[16], float (&avn)[16], int kb) {
    float lmax = 0.f;
    #pragma unroll
    for (int u = 0; u < 16; ++u) lmax = fmaxf(lmax, fabsf(avc[u]));
    pmax[kb & 1][lane][wave] = lmax;
    __syncthreads();   // B1: prev MFMA done reading As/Bs; pmax[kb&1] ready

    // issue B tile stage (async -> LDS)
    #pragma unroll
    for (int c8 = 0; c8 < 8; ++c8)
      gload_lds16(bsrc + (size_t)c8 * 18432 + kb * 128, bdst + c8 * 1024);

    // quantize A row (row = lane, 16 k's)
    floatx4 pm = *(floatx4*)&pmax[kb & 1][lane][0];
    float ma = fmaxf(fmaxf(pm[0], pm[1]), fmaxf(pm[2], pm[3]));
    short8 aq0, aq1;
    if (ma > 0.f) {
      int e = (int)((__builtin_bit_cast(unsigned, ma) >> 23) & 0xffu) - 127;
      if (e < -126) e = -126;
      float inv = make_pow2(6 - e);
      float s   = make_pow2(e - 6);
      #pragma unroll
      for (int u = 0; u < 16; ++u) {
        float r = rintf(avc[u] * inv);
        r = fminf(fmaxf(r, -128.f), 127.f);
        float q = r * s;
        unsigned short hb = (unsigned short)(__builtin_bit_cast(unsigned, q) >> 16);
        if (u < 8) aq0[u] = (short)hb; else aq1[u - 8] = (short)hb;
      }
    } else {
      aq0 = (short8)0; aq1 = (short8)0;
    }
    {
      char* arow = (char*)As + lane * 128;
      int kx = wave * 32;
      *(short8*)(arow + ((kx)      ^ ((lane & 7) << 4))) = aq0;
      *(short8*)(arow + ((kx + 16) ^ ((lane & 7) << 4))) = aq1;
    }
    __syncthreads();   // B2: tiles ready (vmcnt drained -> Bs landed)

    // prefetch next A block; latency hides under the MFMA section
    if (kb < 17) gather(avn, kb + 1);

    // MFMA, swapped operands: D[co][pix] so epilogue stores are coalesced
    #pragma unroll
    for (int ks = 0; ks < 2; ++ks) {
      const int kbyte = (ks * 64 + lk) ^ swz;
      bf16x8 afr[4], bfr[4];
      #pragma unroll
      for (int f = 0; f < 4; ++f) {
        afr[f] = __builtin_bit_cast(bf16x8,
            *(const short8*)((const char*)As + (f * 16 + lr) * 128 + kbyte));
        bfr[f] = __builtin_bit_cast(bf16x8,
            *(const short8*)((const char*)Bs + (wave * 64 + f * 16 + lr) * 128 + kbyte));
      }
      #pragma unroll
      for (int fm = 0; fm < 4; ++fm)
        #pragma unroll
        for (int fn = 0; fn < 4; ++fn)
          acc[fm][fn] = __builtin_amdgcn_mfma_f32_16x16x32_bf16(bfr[fn], afr[fm], acc[fm][fn], 0, 0, 0);
    }
  };

  float av0[16], av1[16];
  gather(av0, 0);
  #pragma unroll 1
  for (int kb = 0; kb < 18; kb += 2) {
    step(av0, av1, kb);
    step(av1, av0, kb + 1);
  }

  // ---- epilogue: D[co][pix]: pix = fm*16 + (lane&15), co = wave*64+fn*16+(lane>>4)*4+r ----
  // 3136 = 49*64, so each 64-row tile lies in exactly one image.
  const unsigned ni = (mt * 64u) / 3136u;
  const unsigned pp0 = mt * 64u - ni * 3136u;
  float* obase = out + (size_t)ni * 802816u + pp0;
  const int cg = (lane >> 4) << 2;
  #pragma unroll
  for (int fn = 0; fn < 4; ++fn) {
    #pragma unroll
    for (int r = 0; r < 4; ++r) {
      int co = wave * 64 + fn * 16 + cg + r;
      float bco = bias[co];
      float* orow = obase + (size_t)co * 3136u;
      #pragma unroll
      for (int fm = 0; fm < 4; ++fm)
        orow[fm * 16 + lr] = acc[fm][fn][r] + bco;
    }
  }
}

extern "C" void kernel_launch(void* const* d_in, const int* in_sizes, int n_in,
                              void* d_out, int out_size, void* d_ws, size_t ws_size,
                              hipStream_t stream) {
  const float* in   = (const float*)d_in[0];
  const float* w    = (const float*)d_in[1];
  const float* bias = (const float*)d_in[2];
  float* out = (float*)d_out;
  unsigned short* qw = (unsigned short*)d_ws;   // 256*1152*2 = 589824 B

  quant_w_kernel<<<4608, 64, 0, stream>>>(w, qw);
  conv_bfp_kernel<<<1568, 256, 0, stream>>>(in, qw, bias, out);
}

// Round 4
// 162.977 us; speedup vs baseline: 1.0186x; 1.0186x over previous
//
#include <hip/hip_runtime.h>

typedef short short8 __attribute__((ext_vector_type(8)));
typedef __bf16 bf16x8 __attribute__((ext_vector_type(8)));
typedef float floatx4 __attribute__((ext_vector_type(4)));

__device__ __forceinline__ float make_pow2(int e) {
  return __builtin_bit_cast(float, (unsigned)((e + 127) << 23));
}

typedef __attribute__((address_space(3))) void lds_void;
typedef const __attribute__((address_space(1))) void glob_void;
__device__ __forceinline__ void gload_lds16(const void* g, void* l) {
  __builtin_amdgcn_global_load_lds((glob_void*)g, (lds_void*)l, 16, 0, 0);
}

// ---------------- Phase 1: quantize weights -> bf16 in workspace ----------------
__global__ void quant_w_kernel(const float* __restrict__ w, unsigned short* __restrict__ qw) {
  int b = blockIdx.x;                 // 0..4607
  int row = b / 18, kb = b - row * 18;
  int t = threadIdx.x;                // 0..63
  int idx = row * 1152 + kb * 64 + t;
  float v = w[idx];
  float a = fabsf(v);
  #pragma unroll
  for (int off = 32; off; off >>= 1) a = fmaxf(a, __shfl_xor(a, off));
  float q = 0.f;
  if (a > 0.f) {
    int e = (int)((__builtin_bit_cast(unsigned, a) >> 23) & 0xffu) - 127;
    if (e < -126) e = -126;
    float inv = make_pow2(6 - e);
    float s   = make_pow2(e - 6);
    float r = rintf(v * inv);
    r = fminf(fmaxf(r, -128.f), 127.f);
    q = r * s;
  }
  qw[idx] = (unsigned short)(__builtin_bit_cast(unsigned, q) >> 16);
}

// ---------------- Phase 2: fused im2col + BFP-quantize + GEMM ----------------
// M=100352, N=256, K=1152. BM=64, BN=256, BK=64. 4 waves, each 64-col slab.
// Depth-3 pipeline: phase kb does MFMA(kb), quantize(kb+1), stage B(kb+1),
// gather(kb+2). All loads issued in a phase complete before its end barrier,
// so __syncthreads' implicit vmcnt(0) drain is free.
__global__ __launch_bounds__(256) void conv_bfp_kernel(
    const float* __restrict__ in, const unsigned short* __restrict__ qw,
    const float* __restrict__ bias, float* __restrict__ out) {
  __shared__ unsigned short As[64 * 64];       // 8 KB single-buffer (frags preloaded)
  __shared__ unsigned short Bs[2][256 * 64];   // 64 KB double-buffer
  __shared__ float pmax[2][64][5];             // padded stride 5: no bank conflict

  const int bid = blockIdx.x;
  const int mt = (bid & 7) * 196 + (bid >> 3);   // XCD-chunked swizzle (1568 = 8*196)
  const int t = threadIdx.x;
  const int lane = t & 63;
  const int wave = __builtin_amdgcn_readfirstlane(t >> 6);

  // ---- pixel geometry (row m = lane) ----
  const unsigned m = mt * 64u + lane;
  const unsigned nimg = m / 3136u;
  const unsigned py = m - nimg * 3136u;
  const int y = (int)(py / 56u);
  const int x = (int)(py - (unsigned)y * 56u);
  const int vbase = (int)((nimg * 401408u + (unsigned)y * 56u + (unsigned)x) * 4u);
  int vm = 0;
  #pragma unroll
  for (int i = 0; i < 3; ++i)
    #pragma unroll
    for (int j = 0; j < 3; ++j)
      if ((unsigned)(y + i - 1) < 56u && (unsigned)(x + j - 1) < 56u)
        vm |= 1 << (i * 3 + j);

  // ---- B staging geometry (pre-swizzled source; wave w stages rows w*64..+63) ----
  const int l3 = lane >> 3, l7 = lane & 7;
  const char* bsrc = (const char*)qw + (size_t)((wave * 64 + l3) * 2304) + ((l7 ^ l3) * 16);

  const int lr = lane & 15;
  const int lk = (lane >> 4) << 4;
  const int swz = (lr & 7) << 4;

  floatx4 acc[4][4] = {};

  auto gather = [&](float (&av)[16], int kb) {
    const int k0 = __builtin_amdgcn_readfirstlane(kb * 64 + wave * 16);
    #pragma unroll
    for (int u = 0; u < 16; ++u) {
      int k = k0 + u;                          // scalar
      int c = (int)((unsigned)k / 9u);
      int ij = k - c * 9;
      int soff = c * 3136 + (ij / 3) * 56 + (ij % 3) - 57;
      const char* pk = (const char*)in + (ptrdiff_t)soff * 4;
      float v = 0.f;
      if ((vm >> ij) & 1)
        v = *(const float*)(pk + vbase);       // global_load_dword v, vbase, s[pk]
      av[u] = v;
    }
  };

  auto stage = [&](int kb) {                   // stage k-block kb -> Bs[kb&1]
    char* bdst = (char*)Bs[kb & 1] + wave * 8192;
    #pragma unroll
    for (int c8 = 0; c8 < 8; ++c8)
      gload_lds16(bsrc + (size_t)c8 * 18432 + kb * 128, bdst + c8 * 1024);
  };

  auto lmax_store = [&](float (&av)[16], int kb) {
    float lm = 0.f;
    #pragma unroll
    for (int u = 0; u < 16; ++u) lm = fmaxf(lm, fabsf(av[u]));
    pmax[kb & 1][lane][wave] = lm;
  };

  auto quantWrite = [&](float (&av)[16], int kb) {
    const float* pr = &pmax[kb & 1][lane][0];
    float ma = fmaxf(fmaxf(pr[0], pr[1]), fmaxf(pr[2], pr[3]));
    short8 aq0, aq1;
    if (ma > 0.f) {
      int e = (int)((__builtin_bit_cast(unsigned, ma) >> 23) & 0xffu) - 127;
      if (e < -126) e = -126;
      float inv = make_pow2(6 - e);
      float s   = make_pow2(e - 6);
      #pragma unroll
      for (int u = 0; u < 16; ++u) {
        float r = rintf(av[u] * inv);
        r = fminf(fmaxf(r, -128.f), 127.f);
        float q = r * s;
        unsigned short hb = (unsigned short)(__builtin_bit_cast(unsigned, q) >> 16);
        if (u < 8) aq0[u] = (short)hb; else aq1[u - 8] = (short)hb;
      }
    } else {
      aq0 = (short8)0; aq1 = (short8)0;
    }
    char* arow = (char*)As + lane * 128;
    int kx = wave * 32;
    *(short8*)(arow + ((kx)      ^ ((lane & 7) << 4))) = aq0;
    *(short8*)(arow + ((kx + 16) ^ ((lane & 7) << 4))) = aq1;
  };

  float av0[16], av1[16];

  // ---- prologue ----
  stage(0);
  gather(av0, 0);
  lmax_store(av0, 0);
  __syncthreads();                 // pmax(0) visible; stage(0)+gather(0) drained
  quantWrite(av0, 0);              // As <- kb 0
  gather(av1, 1);
  lmax_store(av1, 1);
  __syncthreads();                 // As(0), pmax(1) visible; gather(1) drained

  auto phase = [&](int kb, float (&avq)[16], float (&avg)[16]) {
    // a: preload this phase's A fragments (As holds kb)
    bf16x8 afr[2][4];
    #pragma unroll
    for (int ks = 0; ks < 2; ++ks)
      #pragma unroll
      for (int f = 0; f < 4; ++f)
        afr[ks][f] = __builtin_bit_cast(bf16x8,
            *(const short8*)((const char*)As + (f * 16 + lr) * 128 + ((ks * 64 + lk) ^ swz)));
    __syncthreads();               // b: all waves' A reads done -> As reusable

    if (kb < 17) {
      quantWrite(avq, kb + 1);     // As <- kb+1 (uses pmax[(kb+1)&1])
      stage(kb + 1);               // Bs[(kb+1)&1] (free since phase kb-1)
    }
    if (kb < 16) gather(avg, kb + 2);

    // f: MFMA (swapped operands -> D[co][pix])
    const char* bbase = (const char*)Bs[kb & 1];
    #pragma unroll
    for (int ks = 0; ks < 2; ++ks) {
      const int kbyte = (ks * 64 + lk) ^ swz;
      bf16x8 bfr[4];
      #pragma unroll
      for (int f = 0; f < 4; ++f)
        bfr[f] = __builtin_bit_cast(bf16x8,
            *(const short8*)(bbase + (wave * 64 + f * 16 + lr) * 128 + kbyte));
      #pragma unroll
      for (int fm = 0; fm < 4; ++fm)
        #pragma unroll
        for (int fn = 0; fn < 4; ++fn)
          acc[fm][fn] = __builtin_amdgcn_mfma_f32_16x16x32_bf16(bfr[fn], afr[ks][fm], acc[fm][fn], 0, 0, 0);
    }

    if (kb < 16) lmax_store(avg, kb + 2);   // waits gather(kb+2); covers stage too
    if (kb < 17) __syncthreads();  // h: As(kb+1)+pmax(kb+2) visible; vmcnt already ~0
  };

  #pragma unroll 1
  for (int kb = 0; kb < 18; kb += 2) {
    phase(kb, av1, av0);
    phase(kb + 1, av0, av1);
  }

  // ---- epilogue: D[co][pix]; 3136 = 49*64 so the 64-row tile is one image ----
  const unsigned ni = (mt * 64u) / 3136u;
  const unsigned pp0 = mt * 64u - ni * 3136u;
  float* obase = out + (size_t)ni * 802816u + pp0;
  const int cg = (lane >> 4) << 2;
  #pragma unroll
  for (int fn = 0; fn < 4; ++fn) {
    #pragma unroll
    for (int r = 0; r < 4; ++r) {
      int co = wave * 64 + fn * 16 + cg + r;
      float bco = bias[co];
      float* orow = obase + (size_t)co * 3136u;
      #pragma unroll
      for (int fm = 0; fm < 4; ++fm)
        orow[fm * 16 + lr] = acc[fm][fn][r] + bco;
    }
  }
}

extern "C" void kernel_launch(void* const* d_in, const int* in_sizes, int n_in,
                              void* d_out, int out_size, void* d_ws, size_t ws_size,
                              hipStream_t stream) {
  const float* in   = (const float*)d_in[0];
  const float* w    = (const float*)d_in[1];
  const float* bias = (const float*)d_in[2];
  float* out = (float*)d_out;
  unsigned short* qw = (unsigned short*)d_ws;   // 256*1152*2 = 589824 B

  quant_w_kernel<<<4608, 64, 0, stream>>>(w, qw);
  conv_bfp_kernel<<<1568, 256, 0, stream>>>(in, qw, bias, out);
}

// Round 5
// 137.492 us; speedup vs baseline: 1.2075x; 1.1854x over previous
//
#include <hip/hip_runtime.h>

typedef short short8 __attribute__((ext_vector_type(8)));
typedef __bf16 bf16x8 __attribute__((ext_vector_type(8)));
typedef float floatx4 __attribute__((ext_vector_type(4)));

__device__ __forceinline__ float make_pow2(int e) {
  return __builtin_bit_cast(float, (unsigned)((e + 127) << 23));
}

typedef __attribute__((address_space(3))) void lds_void;
typedef const __attribute__((address_space(1))) void glob_void;
__device__ __forceinline__ void gload_lds16(const void* g, void* l) {
  __builtin_amdgcn_global_load_lds((glob_void*)g, (lds_void*)l, 16, 0, 0);
}

// ---------------- Phase 1: quantize weights -> bf16 in workspace ----------------
__global__ void quant_w_kernel(const float* __restrict__ w, unsigned short* __restrict__ qw) {
  int b = blockIdx.x;                 // 0..4607
  int row = b / 18, kb = b - row * 18;
  int t = threadIdx.x;                // 0..63
  int idx = row * 1152 + kb * 64 + t;
  float v = w[idx];
  float a = fabsf(v);
  #pragma unroll
  for (int off = 32; off; off >>= 1) a = fmaxf(a, __shfl_xor(a, off));
  float q = 0.f;
  if (a > 0.f) {
    int e = (int)((__builtin_bit_cast(unsigned, a) >> 23) & 0xffu) - 127;
    if (e < -126) e = -126;
    float inv = make_pow2(6 - e);
    float s   = make_pow2(e - 6);
    float r = rintf(v * inv);
    r = fminf(fmaxf(r, -128.f), 127.f);
    q = r * s;
  }
  qw[idx] = (unsigned short)(__builtin_bit_cast(unsigned, q) >> 16);
}

// ---------------- Phase 2: fused im2col + BFP-quantize + GEMM ----------------
// M=100352, N=256, K=1152. BM=64, BN=256, BK=64. 512 thr = 8 waves; wave owns a
// 32-col N-slab (acc[4][2]) and an 8-wide k-slice of the A gather/quantize.
// Depth-3 pipeline: phase kb = MFMA(kb) + quantize(kb+1) + stageB(kb+1) + gather(kb+2).
__global__ __launch_bounds__(512, 4) void conv_bfp_kernel(
    const float* __restrict__ in, const unsigned short* __restrict__ qw,
    const float* __restrict__ bias, float* __restrict__ out) {
  __shared__ unsigned short As[64 * 64];       // 8 KB single-buffer (frags preloaded)
  __shared__ unsigned short Bs[2][256 * 64];   // 64 KB double-buffer
  __shared__ float pmax[2][8][64];             // [buf][wave][row], conflict-free

  const int bid = blockIdx.x;
  const int mt = (bid & 7) * 196 + (bid >> 3);   // XCD-chunked swizzle (1568 = 8*196)
  const int t = threadIdx.x;
  const int lane = t & 63;
  const int wave = __builtin_amdgcn_readfirstlane(t >> 6);

  // ---- pixel geometry (A row = lane) ----
  const unsigned m = mt * 64u + lane;
  const unsigned nimg = m / 3136u;
  const unsigned py = m - nimg * 3136u;
  const int y = (int)(py / 56u);
  const int x = (int)(py - (unsigned)y * 56u);
  const int vbase = (int)((nimg * 401408u + (unsigned)y * 56u + (unsigned)x) * 4u);
  int vm = 0;
  #pragma unroll
  for (int i = 0; i < 3; ++i)
    #pragma unroll
    for (int j = 0; j < 3; ++j)
      if ((unsigned)(y + i - 1) < 56u && (unsigned)(x + j - 1) < 56u)
        vm |= 1 << (i * 3 + j);

  // ---- B staging (wave w stages rows w*32..+31; pre-swizzled source chunks) ----
  const int l3 = lane >> 3, l7 = lane & 7;
  const char* bsrc = (const char*)qw + (size_t)((wave * 32 + l3) * 2304) + ((l7 ^ l3) * 16);

  const int lr = lane & 15;
  const int lk = (lane >> 4) << 4;
  const int swz = (lr & 7) << 4;

  floatx4 acc[4][2] = {};

  auto gather = [&](float (&av)[8], int kb) {
    const int k0 = __builtin_amdgcn_readfirstlane(kb * 64 + wave * 8);
    #pragma unroll
    for (int u = 0; u < 8; ++u) {
      int k = k0 + u;                          // scalar
      int c = (int)((unsigned)k / 9u);
      int ij = k - c * 9;
      int soff = c * 3136 + (ij / 3) * 56 + (ij % 3) - 57;
      const char* pk = (const char*)in + (ptrdiff_t)soff * 4;
      float v = 0.f;
      if ((vm >> ij) & 1)
        v = *(const float*)(pk + vbase);       // global_load_dword v, vbase, s[pk]
      av[u] = v;
    }
  };

  auto stage = [&](int kb) {                   // stage k-block kb -> Bs[kb&1]
    char* bdst = (char*)Bs[kb & 1] + wave * 4096;
    #pragma unroll
    for (int c8 = 0; c8 < 4; ++c8)
      gload_lds16(bsrc + (size_t)c8 * 18432 + kb * 128, bdst + c8 * 1024);
  };

  auto lmax_store = [&](float (&av)[8], int kb) {
    float lm = 0.f;
    #pragma unroll
    for (int u = 0; u < 8; ++u) lm = fmaxf(lm, fabsf(av[u]));
    pmax[kb & 1][wave][lane] = lm;
  };

  auto quantWrite = [&](float (&av)[8], int kb) {
    const float* pb = &pmax[kb & 1][0][lane];
    float ma = 0.f;
    #pragma unroll
    for (int j = 0; j < 8; ++j) ma = fmaxf(ma, pb[j * 64]);
    short8 aq;
    if (ma > 0.f) {
      int e = (int)((__builtin_bit_cast(unsigned, ma) >> 23) & 0xffu) - 127;
      if (e < -126) e = -126;
      float inv = make_pow2(6 - e);
      float s   = make_pow2(e - 6);
      #pragma unroll
      for (int u = 0; u < 8; ++u) {
        float r = rintf(av[u] * inv);
        r = fminf(fmaxf(r, -128.f), 127.f);
        float q = r * s;
        aq[u] = (short)(unsigned short)(__builtin_bit_cast(unsigned, q) >> 16);
      }
    } else {
      aq = (short8)0;
    }
    char* arow = (char*)As + lane * 128;
    *(short8*)(arow + ((wave * 16) ^ ((lane & 7) << 4))) = aq;
  };

  float av0[8], av1[8];

  // ---- prologue ----
  stage(0);
  gather(av0, 0);
  lmax_store(av0, 0);
  __syncthreads();                 // pmax(0) visible; stage(0)+gather(0) drained
  quantWrite(av0, 0);              // As <- kb 0
  gather(av1, 1);
  lmax_store(av1, 1);
  __syncthreads();                 // As(0), pmax(1) visible; gather(1) drained

  auto phase = [&](int kb, float (&avq)[8], float (&avg)[8]) {
    // a: preload this phase's A fragments (As holds kb)
    bf16x8 afr[2][4];
    #pragma unroll
    for (int ks = 0; ks < 2; ++ks)
      #pragma unroll
      for (int f = 0; f < 4; ++f)
        afr[ks][f] = __builtin_bit_cast(bf16x8,
            *(const short8*)((const char*)As + (f * 16 + lr) * 128 + ((ks * 64 + lk) ^ swz)));
    __syncthreads();               // b: all waves' A reads done -> As reusable

    if (kb < 17) {
      quantWrite(avq, kb + 1);     // As <- kb+1 (uses pmax[(kb+1)&1])
      stage(kb + 1);               // Bs[(kb+1)&1] (free since phase kb-1)
    }
    if (kb < 16) gather(avg, kb + 2);

    // MFMA (swapped operands -> D[co][pix])
    const char* bbase = (const char*)Bs[kb & 1];
    #pragma unroll
    for (int ks = 0; ks < 2; ++ks) {
      const int kbyte = (ks * 64 + lk) ^ swz;
      bf16x8 bfr[2];
      #pragma unroll
      for (int f = 0; f < 2; ++f)
        bfr[f] = __builtin_bit_cast(bf16x8,
            *(const short8*)(bbase + (wave * 32 + f * 16 + lr) * 128 + kbyte));
      #pragma unroll
      for (int fm = 0; fm < 4; ++fm)
        #pragma unroll
        for (int fn = 0; fn < 2; ++fn)
          acc[fm][fn] = __builtin_amdgcn_mfma_f32_16x16x32_bf16(bfr[fn], afr[ks][fm], acc[fm][fn], 0, 0, 0);
    }

    if (kb < 16) lmax_store(avg, kb + 2);   // waits gather(kb+2); covers stage too
    if (kb < 17) __syncthreads();  // h: As(kb+1)+pmax(kb+2) visible; vmcnt already ~0
  };

  #pragma unroll 1
  for (int kb = 0; kb < 18; kb += 2) {
    phase(kb, av1, av0);
    phase(kb + 1, av0, av1);
  }

  // ---- epilogue: D[co][pix]; 3136 = 49*64 so the 64-row tile is one image ----
  const unsigned ni = (mt * 64u) / 3136u;
  const unsigned pp0 = mt * 64u - ni * 3136u;
  float* obase = out + (size_t)ni * 802816u + pp0;
  const int cg = (lane >> 4) << 2;
  #pragma unroll
  for (int fn = 0; fn < 2; ++fn) {
    floatx4 bv = *(const floatx4*)&bias[wave * 32 + fn * 16 + cg];
    #pragma unroll
    for (int r = 0; r < 4; ++r) {
      int co = wave * 32 + fn * 16 + cg + r;
      float* orow = obase + (size_t)co * 3136u;
      #pragma unroll
      for (int fm = 0; fm < 4; ++fm)
        orow[fm * 16 + lr] = acc[fm][fn][r] + bv[r];
    }
  }
}

extern "C" void kernel_launch(void* const* d_in, const int* in_sizes, int n_in,
                              void* d_out, int out_size, void* d_ws, size_t ws_size,
                              hipStream_t stream) {
  const float* in   = (const float*)d_in[0];
  const float* w    = (const float*)d_in[1];
  const float* bias = (const float*)d_in[2];
  float* out = (float*)d_out;
  unsigned short* qw = (unsigned short*)d_ws;   // 256*1152*2 = 589824 B

  quant_w_kernel<<<4608, 64, 0, stream>>>(w, qw);
  conv_bfp_kernel<<<1568, 512, 0, stream>>>(in, qw, bias, out);
}